// Round 1
// baseline (349.907 us; speedup 1.0000x reference)
//
#include <hip/hip_runtime.h>

// ---- problem constants (fixed by reference setup_inputs) ----
constexpr int B_  = 32;
constexpr int Na  = 512;
constexpr int Nv  = 256;
constexpr int D   = 384;

constexpr int BK  = 32;    // k-chunk staged per iteration
constexpr int BN  = 128;   // n rows per block chunk (4 waves * 32 rows)
constexpr int LDK = 40;    // padded LDS row stride in elements (80 B -> only 2-way bank alias, free)

typedef short  bf16x8  __attribute__((ext_vector_type(8)));
typedef float  floatx4 __attribute__((ext_vector_type(4)));
typedef unsigned short ushort8 __attribute__((ext_vector_type(8)));

// fp32 -> bf16 with round-to-nearest-even (3 VALU ops, no lib dependency)
__device__ __forceinline__ unsigned short f2bf(float f) {
    unsigned int u = __float_as_uint(f);
    u += 0x7fffu + ((u >> 16) & 1u);
    return (unsigned short)(u >> 16);
}

__global__ __launch_bounds__(256, 2) void fused_sim_kernel(
        const float* __restrict__ audio,
        const float* __restrict__ visual,
        float* __restrict__ out)
{
    __shared__ unsigned short alds[BN * LDK];   // 10240 B
    __shared__ unsigned short blds[Nv * LDK];   // 20480 B
    __shared__ float wsum[4];

    const int bid  = blockIdx.x;
    const int bi   = bid >> 5;     // audio batch index  (row of output)
    const int bj   = bid & 31;     // visual batch index (col of output)
    const int tid  = threadIdx.x;
    const int lane = tid & 63;
    const int wave = tid >> 6;

    const float* Abase = audio  + (size_t)bi * Na * D;
    const float* Bbase = visual + (size_t)bj * Nv * D;

    const int fr = lane & 15;          // free index within a 16-tile
    const int qk = (lane >> 4) * 8;    // this lane's k offset inside a 32-k chunk

    // per-lane partial sum of row-lse values (each value replicated across a
    // 16-lane group; groups hold disjoint row sets, so reduce across groups only)
    float row_acc = 0.0f;

    for (int n0 = 0; n0 < Na; n0 += BN) {
        floatx4 acc[2][16];
        #pragma unroll
        for (int a = 0; a < 2; ++a)
            #pragma unroll
            for (int mt = 0; mt < 16; ++mt)
                acc[a][mt] = (floatx4){0.f, 0.f, 0.f, 0.f};

        for (int k0 = 0; k0 < D; k0 += BK) {
            // ---- stage A chunk: BN x BK fp32 -> bf16 LDS ----
            {
                const int row = tid >> 1;
                const int kof = (tid & 1) * 16;
                const float* src = Abase + (size_t)(n0 + row) * D + (k0 + kof);
                float4 f0 = ((const float4*)src)[0];
                float4 f1 = ((const float4*)src)[1];
                float4 f2 = ((const float4*)src)[2];
                float4 f3 = ((const float4*)src)[3];
                ushort8 p0 = { f2bf(f0.x), f2bf(f0.y), f2bf(f0.z), f2bf(f0.w),
                               f2bf(f1.x), f2bf(f1.y), f2bf(f1.z), f2bf(f1.w) };
                ushort8 p1 = { f2bf(f2.x), f2bf(f2.y), f2bf(f2.z), f2bf(f2.w),
                               f2bf(f3.x), f2bf(f3.y), f2bf(f3.z), f2bf(f3.w) };
                *(ushort8*)&alds[row * LDK + kof]     = p0;
                *(ushort8*)&alds[row * LDK + kof + 8] = p1;
            }
            // ---- stage B chunk: Nv x BK fp32 -> bf16 LDS (thread t = row t) ----
            {
                const float* src = Bbase + (size_t)tid * D + k0;
                #pragma unroll
                for (int h = 0; h < 4; ++h) {
                    float4 fa = ((const float4*)src)[2*h];
                    float4 fb = ((const float4*)src)[2*h+1];
                    ushort8 p = { f2bf(fa.x), f2bf(fa.y), f2bf(fa.z), f2bf(fa.w),
                                  f2bf(fb.x), f2bf(fb.y), f2bf(fb.z), f2bf(fb.w) };
                    *(ushort8*)&blds[tid * LDK + 8*h] = p;
                }
            }
            __syncthreads();

            // ---- MFMA: wave covers rows [wave*32, wave*32+32) x all 256 cols ----
            bf16x8 a0 = *(const bf16x8*)&alds[(wave * 32 +      fr) * LDK + qk];
            bf16x8 a1 = *(const bf16x8*)&alds[(wave * 32 + 16 + fr) * LDK + qk];
            #pragma unroll
            for (int mt = 0; mt < 16; ++mt) {
                bf16x8 bfr = *(const bf16x8*)&blds[(mt * 16 + fr) * LDK + qk];
                acc[0][mt] = __builtin_amdgcn_mfma_f32_16x16x32_bf16(a0, bfr, acc[0][mt], 0, 0, 0);
                acc[1][mt] = __builtin_amdgcn_mfma_f32_16x16x32_bf16(a1, bfr, acc[1][mt], 0, 0, 0);
            }
            __syncthreads();
        }

        // ---- epilogue: per-row logsumexp over all 256 cols, accumulate mean ----
        // C/D layout: col = mt*16 + (lane&15), row = (lane>>4)*4 + reg
        constexpr float INV_TAU_LN2 = 0.7213475204444817f;  // 1/(tau*ln2), tau=2
        constexpr float TAU_LN2     = 1.3862943611198906f;  // tau*ln2

        #pragma unroll
        for (int a = 0; a < 2; ++a) {
            #pragma unroll
            for (int r = 0; r < 4; ++r) {
                float vmax = acc[a][0][r];
                #pragma unroll
                for (int mt = 1; mt < 16; ++mt) vmax = fmaxf(vmax, acc[a][mt][r]);
                #pragma unroll
                for (int m = 1; m < 16; m <<= 1)
                    vmax = fmaxf(vmax, __shfl_xor(vmax, m, 64));
                float s = 0.f;
                #pragma unroll
                for (int mt = 0; mt < 16; ++mt)
                    s += exp2f((acc[a][mt][r] - vmax) * INV_TAU_LN2);
                #pragma unroll
                for (int m = 1; m < 16; m <<= 1)
                    s += __shfl_xor(s, m, 64);
                row_acc += vmax + TAU_LN2 * log2f(s);
            }
        }
    }

    // reduce across the 4 quad-groups of the wave (within-group values identical)
    row_acc += __shfl_xor(row_acc, 16, 64);
    row_acc += __shfl_xor(row_acc, 32, 64);
    if (lane == 0) wsum[wave] = row_acc;
    __syncthreads();
    if (tid == 0)
        out[bid] = (wsum[0] + wsum[1] + wsum[2] + wsum[3]) * (1.0f / Na);
}

extern "C" void kernel_launch(void* const* d_in, const int* in_sizes, int n_in,
                              void* d_out, int out_size, void* d_ws, size_t ws_size,
                              hipStream_t stream) {
    const float* audio  = (const float*)d_in[0];
    const float* visual = (const float*)d_in[1];
    float* out = (float*)d_out;
    fused_sim_kernel<<<dim3(B_ * B_), dim3(256), 0, stream>>>(audio, visual, out);
}

// Round 2
// 286.618 us; speedup vs baseline: 1.2208x; 1.2208x over previous
//
#include <hip/hip_runtime.h>

// ---- problem constants (fixed by reference setup_inputs) ----
constexpr int B_  = 32;
constexpr int Na  = 512;
constexpr int Nv  = 256;
constexpr int D   = 384;

constexpr int BK  = 32;    // k-chunk per iteration
constexpr int BN  = 128;   // audio rows per block (one n-chunk)
constexpr int NCH = Na / BN;   // 4 n-chunks -> grid = 32*32*4

typedef short  bf16x8  __attribute__((ext_vector_type(8)));
typedef float  floatx4 __attribute__((ext_vector_type(4)));
typedef unsigned short ushort8v __attribute__((ext_vector_type(8)));

// fp32 -> bf16 round-to-nearest-even
__device__ __forceinline__ unsigned short f2bf(float f) {
    unsigned int u = __float_as_uint(f);
    u += 0x7fffu + ((u >> 16) & 1u);
    return (unsigned short)(u >> 16);
}

// 16B-per-lane async global->LDS (lane i writes LDS slot base + i*16)
__device__ __forceinline__ void async_load16(const void* g, void* l) {
    __builtin_amdgcn_global_load_lds(
        (const __attribute__((address_space(1))) unsigned int*)g,
        (__attribute__((address_space(3))) unsigned int*)l,
        16, 0, 0);
}

// ---- K0: zero the 1024-float output (it is poisoned before every launch) ----
__global__ void zero_out_kernel(float* __restrict__ out) {
    out[blockIdx.x * 256 + threadIdx.x] = 0.0f;
}

// ---- K1: one-shot fp32 -> bf16 conversion of both inputs into workspace ----
__global__ void convert_kernel(const float* __restrict__ a, const float* __restrict__ v,
                               unsigned short* __restrict__ abf, unsigned short* __restrict__ vbf) {
    constexpr int NA8 = B_ * Na * D / 8;   // 786,432 float8 groups
    constexpr int NV8 = B_ * Nv * D / 8;   // 393,216
    int stride = gridDim.x * blockDim.x;
    for (int i = blockIdx.x * blockDim.x + threadIdx.x; i < NA8 + NV8; i += stride) {
        const float4* src;
        unsigned short* dst;
        int j;
        if (i < NA8) { src = (const float4*)a; dst = abf; j = i; }
        else         { src = (const float4*)v; dst = vbf; j = i - NA8; }
        float4 f0 = src[2 * j];
        float4 f1 = src[2 * j + 1];
        ushort8v o = { f2bf(f0.x), f2bf(f0.y), f2bf(f0.z), f2bf(f0.w),
                       f2bf(f1.x), f2bf(f1.y), f2bf(f1.z), f2bf(f1.w) };
        *(ushort8v*)&dst[j * 8] = o;
    }
}

// ---- K2: fused bf16 GEMM + logsumexp-pool, one (i, j, n-chunk) per block ----
// LDS layout (per 16-row group g): addr(row r, 16B-chunk c) = g*1024 + c*256 + (r&15)*16
// matches global_load_lds lane order: lane i -> row (i&15), chunk (i>>4).
// ds_read_b128 fragment reads then hit dword-banks (fr*4+w)%32 -> only free 2-way alias.
__global__ __launch_bounds__(256, 3) void gemm_lse_kernel(
        const unsigned short* __restrict__ abf,
        const unsigned short* __restrict__ vbf,
        float* __restrict__ out)
{
    __shared__ unsigned short alds[BN * BK];   // 8 KB  (8 groups of 1024 B)
    __shared__ unsigned short blds[Nv * BK];   // 16 KB (16 groups)
    __shared__ float wsum[4];

    const int bid  = blockIdx.x;
    const int nc   = bid & 3;
    const int bj   = (bid >> 2) & 31;
    const int bi   = bid >> 7;
    const int tid  = threadIdx.x;
    const int lane = tid & 63;
    const int wave = tid >> 6;
    const int fr   = lane & 15;    // free index within a 16-tile / staging row-in-group
    const int g    = lane >> 4;    // k-quarter / staging chunk index

    const unsigned short* Ab = abf + ((size_t)bi * Na + nc * BN) * D;
    const unsigned short* Bb = vbf + (size_t)bj * Nv * D;

    // staging source pointers (advance by BK elems per k-iter)
    const unsigned short* ag[2];
    const unsigned short* bg[4];
    unsigned short* aldst[2];
    unsigned short* bldst[4];
    #pragma unroll
    for (int q = 0; q < 2; ++q) {
        int grp = wave * 2 + q;
        ag[q]    = Ab + (size_t)(grp * 16 + fr) * D + g * 8;
        aldst[q] = &alds[grp * 512];
    }
    #pragma unroll
    for (int q = 0; q < 4; ++q) {
        int grp = wave * 4 + q;
        bg[q]    = Bb + (size_t)(grp * 16 + fr) * D + g * 8;
        bldst[q] = &blds[grp * 512];
    }

    floatx4 acc[2][16];
    #pragma unroll
    for (int a = 0; a < 2; ++a)
        #pragma unroll
        for (int mt = 0; mt < 16; ++mt)
            acc[a][mt] = (floatx4){0.f, 0.f, 0.f, 0.f};

    for (int k0 = 0; k0 < D; k0 += BK) {
        #pragma unroll
        for (int q = 0; q < 2; ++q) { async_load16(ag[q], aldst[q]); ag[q] += BK; }
        #pragma unroll
        for (int q = 0; q < 4; ++q) { async_load16(bg[q], bldst[q]); bg[q] += BK; }
        __syncthreads();

        bf16x8 a0 = *(const bf16x8*)&alds[(wave * 2 + 0) * 512 + g * 128 + fr * 8];
        bf16x8 a1 = *(const bf16x8*)&alds[(wave * 2 + 1) * 512 + g * 128 + fr * 8];
        #pragma unroll
        for (int mt = 0; mt < 16; ++mt) {
            bf16x8 bfr = *(const bf16x8*)&blds[mt * 512 + g * 128 + fr * 8];
            acc[0][mt] = __builtin_amdgcn_mfma_f32_16x16x32_bf16(a0, bfr, acc[0][mt], 0, 0, 0);
            acc[1][mt] = __builtin_amdgcn_mfma_f32_16x16x32_bf16(a1, bfr, acc[1][mt], 0, 0, 0);
        }
        __syncthreads();
    }

    // ---- epilogue: per-row logsumexp over all 256 cols ----
    // C/D layout: col = mt*16 + (lane&15), row = (lane>>4)*4 + reg
    constexpr float INV_TAU_LN2 = 0.7213475204444817f;  // 1/(tau*ln2), tau=2
    constexpr float TAU_LN2     = 1.3862943611198906f;  // tau*ln2

    float row_acc = 0.0f;
    #pragma unroll
    for (int a = 0; a < 2; ++a) {
        #pragma unroll
        for (int r = 0; r < 4; ++r) {
            float vmax = acc[a][0][r];
            #pragma unroll
            for (int mt = 1; mt < 16; ++mt) vmax = fmaxf(vmax, acc[a][mt][r]);
            #pragma unroll
            for (int m = 1; m < 16; m <<= 1)
                vmax = fmaxf(vmax, __shfl_xor(vmax, m, 64));
            float s = 0.f;
            #pragma unroll
            for (int mt = 0; mt < 16; ++mt)
                s += exp2f((acc[a][mt][r] - vmax) * INV_TAU_LN2);
            #pragma unroll
            for (int m = 1; m < 16; m <<= 1)
                s += __shfl_xor(s, m, 64);
            row_acc += vmax + TAU_LN2 * log2f(s);
        }
    }

    row_acc += __shfl_xor(row_acc, 16, 64);
    row_acc += __shfl_xor(row_acc, 32, 64);
    if (lane == 0) wsum[wave] = row_acc;
    __syncthreads();
    if (tid == 0)
        atomicAdd(&out[bi * 32 + bj],
                  (wsum[0] + wsum[1] + wsum[2] + wsum[3]) * (1.0f / Na));
}

extern "C" void kernel_launch(void* const* d_in, const int* in_sizes, int n_in,
                              void* d_out, int out_size, void* d_ws, size_t ws_size,
                              hipStream_t stream) {
    const float* audio  = (const float*)d_in[0];
    const float* visual = (const float*)d_in[1];
    float* out = (float*)d_out;

    unsigned short* abf = (unsigned short*)d_ws;                       // 12.58 MB
    unsigned short* vbf = abf + (size_t)B_ * Na * D;                   // +6.29 MB

    zero_out_kernel<<<dim3(4), dim3(256), 0, stream>>>(out);
    convert_kernel<<<dim3(2048), dim3(256), 0, stream>>>(audio, visual, abf, vbf);
    gemm_lse_kernel<<<dim3(B_ * B_ * NCH), dim3(256), 0, stream>>>(abf, vbf, out);
}